// Round 8
// baseline (4276.493 us; speedup 1.0000x reference)
//
#include <hip/hip_runtime.h>
#include <hip/hip_bf16.h>
#include <cstdint>
#include <cstddef>

// ---------------------------------------------------------------------------
// Host-side reproduction of np.random.RandomState(2).permutation(64):
// MT19937 init_genrand(2), Fisher-Yates with numpy random_interval
// (mask+rejection). Mask bit d = (perm[d] >= 38).
// ---------------------------------------------------------------------------
static uint64_t compute_mask_bits() {
    uint32_t mt[624];
    mt[0] = 2u;
    for (int i = 1; i < 624; i++)
        mt[i] = 1812433253u * (mt[i - 1] ^ (mt[i - 1] >> 30)) + (uint32_t)i;
    int mti = 624;
    auto genrand = [&]() -> uint32_t {
        if (mti >= 624) {
            for (int k = 0; k < 624; k++) {
                uint32_t y = (mt[k] & 0x80000000u) | (mt[(k + 1) % 624] & 0x7fffffffu);
                mt[k] = mt[(k + 397) % 624] ^ (y >> 1) ^ ((y & 1u) ? 2567483615u : 0u);
            }
            mti = 0;
        }
        uint32_t y = mt[mti++];
        y ^= y >> 11;
        y ^= (y << 7) & 2636928640u;
        y ^= (y << 15) & 4022730752u;
        y ^= y >> 18;
        return y;
    };
    int arr[64];
    for (int i = 0; i < 64; i++) arr[i] = i;
    for (int i = 63; i >= 1; i--) {
        uint32_t mask = (uint32_t)i;
        mask |= mask >> 1; mask |= mask >> 2; mask |= mask >> 4;
        mask |= mask >> 8; mask |= mask >> 16;
        uint32_t v;
        do { v = genrand() & mask; } while (v > (uint32_t)i);
        int tmp = arr[i]; arr[i] = arr[v]; arr[v] = tmp;
    }
    uint64_t bits = 0;
    for (int d = 0; d < 64; d++)
        if (arr[d] >= 38) bits |= (1ull << d);
    return bits;
}

// ---------------------------------------------------------------------------
// Output-row flag set + compacted list (rows read by the final dot).
// ---------------------------------------------------------------------------
__global__ void flag_kernel(const int* __restrict__ users, const int* __restrict__ items,
                            unsigned char* __restrict__ flag, int B, int U) {
    int i = blockIdx.x * 256 + threadIdx.x;
    if (i < B) flag[users[i]] = 1;
    else if (i < 2 * B) flag[U + items[i - B]] = 1;
}

__global__ void flist_kernel(const unsigned char* __restrict__ flag,
                             int* __restrict__ flist, int* __restrict__ fcount, int n) {
    int i = blockIdx.x * 256 + threadIdx.x;
    if (i < n && flag[i]) {
        int p = atomicAdd(fcount, 1);
        flist[p] = i;
    }
}

// ---------------------------------------------------------------------------
// Per-rating constant c1[r][j] = b1[r][j] + sum_k e_r[k] * W1[r][64+k][j].
// ---------------------------------------------------------------------------
__global__ void c1_kernel(const float* __restrict__ rating_emb, const float* __restrict__ W1,
                          const float* __restrict__ b1, float* __restrict__ c1_all) {
    int r = blockIdx.x;
    int t = threadIdx.x;  // 64 threads
    const float* W1r = W1 + (size_t)r * (128 * 64);
    float acc = b1[r * 64 + t];
    for (int k = 0; k < 64; k++)
        acc += rating_emb[r * 64 + k] * W1r[(64 + k) * 64 + t];
    c1_all[r * 64 + t] = acc;
}

// ---------------------------------------------------------------------------
// XCD-sliced batched histogram: slice = blockIdx.x & 7 (round-robin XCD
// heuristic), rating = blockIdx.y. Each block reads its whole edge chunk but
// counts only rows in its 1/8 row slice -> cnt lines stay in one XCD's L2.
// ---------------------------------------------------------------------------
__global__ void hist_all_kernel(const int* __restrict__ rows, int* __restrict__ cnt,
                                int E, int N, int SLICE_N) {
    int r = blockIdx.y;
    int slice = blockIdx.x & 7;
    int i = (blockIdx.x >> 3) * 256 + threadIdx.x;
    if (i >= E) return;
    int row = rows[(size_t)r * E + i];
    int lo = slice * SLICE_N;
    if (row < lo || row >= lo + SLICE_N) return;
    atomicAdd(&cnt[(size_t)r * N + row], 1);
}

__global__ void scan1_kernel(const int* __restrict__ cnt, int* __restrict__ rp,
                             int* __restrict__ bsums, int n) {
    __shared__ int sh[256];
    int t = threadIdx.x;
    int base = blockIdx.x * 1024 + t * 4;
    int v0 = 0, v1 = 0, v2 = 0, v3 = 0;
    if (base + 3 < n) {
        int4 q = *(const int4*)(cnt + base);
        v0 = q.x; v1 = q.y; v2 = q.z; v3 = q.w;
    } else {
        if (base + 0 < n) v0 = cnt[base + 0];
        if (base + 1 < n) v1 = cnt[base + 1];
        if (base + 2 < n) v2 = cnt[base + 2];
        if (base + 3 < n) v3 = cnt[base + 3];
    }
    int total = v0 + v1 + v2 + v3;
    sh[t] = total;
    __syncthreads();
    for (int off = 1; off < 256; off <<= 1) {
        int x = (t >= off) ? sh[t - off] : 0;
        __syncthreads();
        sh[t] += x;
        __syncthreads();
    }
    int excl = sh[t] - total;
    if (base + 0 < n) rp[base + 0] = excl;
    if (base + 1 < n) rp[base + 1] = excl + v0;
    if (base + 2 < n) rp[base + 2] = excl + v0 + v1;
    if (base + 3 < n) rp[base + 3] = excl + v0 + v1 + v2;
    if (t == 255) bsums[blockIdx.x] = sh[255];
}

__global__ void scan2_kernel(int* __restrict__ bsums, int nb) {
    __shared__ int sh[256];
    int t = threadIdx.x;
    int base = t * 4;
    int v[4]; int s = 0;
    #pragma unroll
    for (int j = 0; j < 4; j++) {
        v[j] = (base + j < nb) ? bsums[base + j] : 0;
        s += v[j];
    }
    sh[t] = s;
    __syncthreads();
    for (int off = 1; off < 256; off <<= 1) {
        int x = (t >= off) ? sh[t - off] : 0;
        __syncthreads();
        sh[t] += x;
        __syncthreads();
    }
    int run = sh[t] - s;
    #pragma unroll
    for (int j = 0; j < 4; j++) {
        if (base + j < nb) bsums[base + j] = run;
        run += v[j];
    }
}

__global__ void scan3_kernel(int* __restrict__ rp, const int* __restrict__ bsums,
                             int n, int e_total) {
    int i = blockIdx.x * 256 + threadIdx.x;
    if (i < n) rp[i] += bsums[i >> 10];
    if (i == 0) rp[n] = e_total;
}

// ---------------------------------------------------------------------------
// XCD-sliced scatter: rank recovered from atomicSub(cnt) (slice-local lines);
// rec positions for one row-slice are contiguous (CSR is row-ordered), so
// stores never share lines across XCDs. Per-rating launch; rec stays E-sized.
// ---------------------------------------------------------------------------
__global__ void scatter_kernel(const int* __restrict__ rows, const int* __restrict__ cols,
                               const float* __restrict__ vals, const int* __restrict__ rp,
                               int* __restrict__ cnt_r, uint2* __restrict__ rec,
                               int E, int ebase, int SLICE_N) {
    int slice = blockIdx.x & 7;
    int i = (blockIdx.x >> 3) * 256 + threadIdx.x;
    if (i >= E) return;
    int row = rows[i];
    int lo = slice * SLICE_N;
    if (row < lo || row >= lo + SLICE_N) return;
    int old = atomicSub(&cnt_r[row], 1);
    int pos = rp[row] - ebase + old - 1;
    rec[pos] = make_uint2((uint32_t)cols[i], __float_as_uint(vals[i]));
}

// ---------------------------------------------------------------------------
// Per-rating MLP: h = leaky_relu(x @ W1a + c1) @ W2 + b2
// LDS: one W tile + one X/T tile (reused) = 33 KB; 16B-group XOR swizzle
// keeps all LDS streams conflict-free. prev = h; out_acc += h (flagged).
// ---------------------------------------------------------------------------
__global__ __launch_bounds__(256) void mlp_kernel(
    const float* __restrict__ user_emb, const float* __restrict__ item_emb,
    const float* __restrict__ W1, const float* __restrict__ W2,
    const float* __restrict__ c1_all, const float* __restrict__ b2,
    float* __restrict__ prev, float* __restrict__ out_acc,
    const unsigned char* __restrict__ flag, int r, int n_rows, int U) {
    __shared__ float sW[64 * 64];   // [k][j], linear
    __shared__ float sX[64 * 64];   // [k][i], group-swizzled; reused for T
    __shared__ float sc1[64];
    __shared__ float sb2v[64];

    int t = threadIdx.x;
    int row0 = blockIdx.x * 64;
    const float* W1r = W1 + (size_t)r * (128 * 64);
    const float* W2r = W2 + (size_t)r * (64 * 64);

    #pragma unroll
    for (int q = 0; q < 4; q++) {
        int f = t + 256 * q;
        int k = f >> 4, c = (f & 15) * 4;
        *(float4*)(sW + k * 64 + c) = *(const float4*)(W1r + k * 64 + c);
    }
    #pragma unroll
    for (int q = 0; q < 4; q++) {
        int f = t + 256 * q;
        int i = f & 63;
        int c = (f >> 6) * 4;
        int nrow = row0 + i;
        float4 xv = make_float4(0.f, 0.f, 0.f, 0.f);
        if (nrow < n_rows) {
            const float* src = (nrow < U) ? (user_emb + (size_t)nrow * 64)
                                          : (item_emb + (size_t)(nrow - U) * 64);
            xv = *(const float4*)(src + c);
        }
        int gi = i >> 2, w = i & 3;
        sX[(c + 0) * 64 + 4 * (gi ^ ((c + 0) & 15)) + w] = xv.x;
        sX[(c + 1) * 64 + 4 * (gi ^ ((c + 1) & 15)) + w] = xv.y;
        sX[(c + 2) * 64 + 4 * (gi ^ ((c + 2) & 15)) + w] = xv.z;
        sX[(c + 3) * 64 + 4 * (gi ^ ((c + 3) & 15)) + w] = xv.w;
    }
    if (t < 64) sc1[t] = c1_all[r * 64 + t];
    else if (t < 128) sb2v[t - 64] = b2[r * 64 + (t - 64)];
    __syncthreads();

    int gi = t & 15;
    int i0 = gi * 4, j0 = (t >> 4) * 4;
    float acc[4][4];
    #pragma unroll
    for (int a = 0; a < 4; a++)
        #pragma unroll
        for (int b = 0; b < 4; b++) acc[a][b] = sc1[j0 + b];
    for (int k = 0; k < 64; k++) {
        float4 xv = *(const float4*)(sX + k * 64 + 4 * (gi ^ (k & 15)));
        float4 wv = *(const float4*)(sW + k * 64 + j0);
        float xs[4] = {xv.x, xv.y, xv.z, xv.w};
        float ws[4] = {wv.x, wv.y, wv.z, wv.w};
        #pragma unroll
        for (int a = 0; a < 4; a++)
            #pragma unroll
            for (int b = 0; b < 4; b++) acc[a][b] += xs[a] * ws[b];
    }
    __syncthreads();

    #pragma unroll
    for (int b = 0; b < 4; b++) {
        int k = j0 + b;
        float4 tv;
        tv.x = (acc[0][b] >= 0.f) ? acc[0][b] : 0.01f * acc[0][b];
        tv.y = (acc[1][b] >= 0.f) ? acc[1][b] : 0.01f * acc[1][b];
        tv.z = (acc[2][b] >= 0.f) ? acc[2][b] : 0.01f * acc[2][b];
        tv.w = (acc[3][b] >= 0.f) ? acc[3][b] : 0.01f * acc[3][b];
        *(float4*)(sX + k * 64 + 4 * (gi ^ (k & 15))) = tv;
    }
    #pragma unroll
    for (int q = 0; q < 4; q++) {
        int f = t + 256 * q;
        int k = f >> 4, c = (f & 15) * 4;
        *(float4*)(sW + k * 64 + c) = *(const float4*)(W2r + k * 64 + c);
    }
    __syncthreads();

    #pragma unroll
    for (int a = 0; a < 4; a++)
        #pragma unroll
        for (int b = 0; b < 4; b++) acc[a][b] = sb2v[j0 + b];
    for (int k = 0; k < 64; k++) {
        float4 xv = *(const float4*)(sX + k * 64 + 4 * (gi ^ (k & 15)));
        float4 wv = *(const float4*)(sW + k * 64 + j0);
        float xs[4] = {xv.x, xv.y, xv.z, xv.w};
        float ws[4] = {wv.x, wv.y, wv.z, wv.w};
        #pragma unroll
        for (int a = 0; a < 4; a++)
            #pragma unroll
            for (int b = 0; b < 4; b++) acc[a][b] += xs[a] * ws[b];
    }
    #pragma unroll
    for (int a = 0; a < 4; a++) {
        int nrow = row0 + i0 + a;
        if (nrow < n_rows) {
            float4 hv = make_float4(acc[a][0], acc[a][1], acc[a][2], acc[a][3]);
            *(float4*)(prev + (size_t)nrow * 64 + j0) = hv;
            if (flag[nrow]) {
                float4 ov = *(const float4*)(out_acc + (size_t)nrow * 64 + j0);
                ov.x += hv.x; ov.y += hv.y; ov.z += hv.z; ov.w += hv.w;
                *(float4*)(out_acc + (size_t)nrow * 64 + j0) = ov;
            }
        }
    }
}

// ---------------------------------------------------------------------------
// Dim-sliced XCD-local SpMM (layers 0/1): slice = blockIdx & 7 handles dims
// [8s,8s+8) of all rows -> per-XCD gather working set = 3.2 MB (L2-resident).
// Wave = 1 row: lane = (edge-subgroup 0..7, dim 0..7); 8 edges in flight;
// reduce via shfl_xor(8/16/32). rec loads + next stores nontemporal.
// ---------------------------------------------------------------------------
__global__ __launch_bounds__(256) void spmm_kernel(
    const float* __restrict__ prev, float* __restrict__ next,
    float* __restrict__ out_acc, const int* __restrict__ rp,
    const uint2* __restrict__ rec, const unsigned char* __restrict__ flag,
    int n, int ebase) {
    int slice = blockIdx.x & 7;
    int row = (blockIdx.x >> 3) * 4 + (threadIdx.x >> 6);
    if (row >= n) return;
    int lane = threadIdx.x & 63;
    int es = lane >> 3;               // edge subgroup 0..7
    int d = slice * 8 + (lane & 7);   // this lane's dim
    int s = rp[row] - ebase, e2 = rp[row + 1] - ebase;
    float a = 0.f;
    int e = s + es;
    for (; e + 8 < e2; e += 16) {
        unsigned long long v0 = __builtin_nontemporal_load(
            (const unsigned long long*)&rec[e]);
        unsigned long long v1 = __builtin_nontemporal_load(
            (const unsigned long long*)&rec[e + 8]);
        a += __uint_as_float((uint32_t)(v0 >> 32)) *
             prev[(size_t)(uint32_t)v0 * 64 + d];
        a += __uint_as_float((uint32_t)(v1 >> 32)) *
             prev[(size_t)(uint32_t)v1 * 64 + d];
    }
    if (e < e2) {
        unsigned long long v0 = __builtin_nontemporal_load(
            (const unsigned long long*)&rec[e]);
        a += __uint_as_float((uint32_t)(v0 >> 32)) *
             prev[(size_t)(uint32_t)v0 * 64 + d];
    }
    a += __shfl_xor(a, 8);
    a += __shfl_xor(a, 16);
    a += __shfl_xor(a, 32);
    if (lane < 8) {
        __builtin_nontemporal_store(a, &next[(size_t)row * 64 + d]);
    } else if (lane < 16 && flag[row]) {
        out_acc[(size_t)row * 64 + d] += a;
    }
}

// ---------------------------------------------------------------------------
// Layer-2 (masked) SpMM over flist rows, same dim-sliced layout.
// ---------------------------------------------------------------------------
__global__ __launch_bounds__(256) void spmm_masked_kernel(
    const float* __restrict__ prev, float* __restrict__ out_acc,
    const int* __restrict__ rp, const uint2* __restrict__ rec,
    unsigned long long maskbits, const int* __restrict__ flist,
    const int* __restrict__ fcount, int ebase) {
    int slice = blockIdx.x & 7;
    int idx = (blockIdx.x >> 3) * 4 + (threadIdx.x >> 6);
    if (idx >= *fcount) return;
    int row = flist[idx];
    int lane = threadIdx.x & 63;
    int es = lane >> 3;
    int d = slice * 8 + (lane & 7);
    int s = rp[row] - ebase, e2 = rp[row + 1] - ebase;
    float a = 0.f;
    int e = s + es;
    for (; e + 8 < e2; e += 16) {
        unsigned long long v0 = __builtin_nontemporal_load(
            (const unsigned long long*)&rec[e]);
        unsigned long long v1 = __builtin_nontemporal_load(
            (const unsigned long long*)&rec[e + 8]);
        a += __uint_as_float((uint32_t)(v0 >> 32)) *
             prev[(size_t)(uint32_t)v0 * 64 + d];
        a += __uint_as_float((uint32_t)(v1 >> 32)) *
             prev[(size_t)(uint32_t)v1 * 64 + d];
    }
    if (e < e2) {
        unsigned long long v0 = __builtin_nontemporal_load(
            (const unsigned long long*)&rec[e]);
        a += __uint_as_float((uint32_t)(v0 >> 32)) *
             prev[(size_t)(uint32_t)v0 * 64 + d];
    }
    a += __shfl_xor(a, 8);
    a += __shfl_xor(a, 16);
    a += __shfl_xor(a, 32);
    if (lane < 8) {
        float pv = prev[(size_t)row * 64 + d];
        float res = ((maskbits >> d) & 1ull) ? a : pv;
        out_acc[(size_t)row * 64 + d] += res;
    }
}

// ---------------------------------------------------------------------------
// Final: out[b] = (1/R^2) * dot(out_acc[users[b]], out_acc[U+items[b]])
// ---------------------------------------------------------------------------
__global__ __launch_bounds__(256) void dot_kernel(
    const float* __restrict__ out_acc, const int* __restrict__ users,
    const int* __restrict__ items, float* __restrict__ out,
    int Bn, int U, float scale) {
    int w = (int)((blockIdx.x * (unsigned)blockDim.x + threadIdx.x) >> 6);
    int lane = threadIdx.x & 63;
    if (w >= Bn) return;
    int u = users[w], it = items[w];
    float a = out_acc[(size_t)u * 64 + lane];
    float c = out_acc[((size_t)(U + it)) * 64 + lane];
    float p = a * c;
    #pragma unroll
    for (int off = 32; off > 0; off >>= 1) p += __shfl_down(p, off);
    if (lane == 0) out[w] = p * scale;
}

// ---------------------------------------------------------------------------
extern "C" void kernel_launch(void* const* d_in, const int* in_sizes, int n_in,
                              void* d_out, int out_size, void* d_ws, size_t ws_size,
                              hipStream_t stream) {
    const int* users = (const int*)d_in[0];
    const int* items = (const int*)d_in[1];
    const float* user_emb = (const float*)d_in[2];
    const float* item_emb = (const float*)d_in[3];
    const float* rating_emb = (const float*)d_in[4];
    const float* W1 = (const float*)d_in[5];
    const float* b1 = (const float*)d_in[6];
    const float* W2 = (const float*)d_in[7];
    const float* b2 = (const float*)d_in[8];
    const int* rows = (const int*)d_in[9];
    const int* cols = (const int*)d_in[10];
    const float* vals = (const float*)d_in[11];
    float* out = (float*)d_out;

    const int Dd = 64;
    int U = in_sizes[2] / Dd;
    int I = in_sizes[3] / Dd;
    int R = in_sizes[4] / Dd;
    int N = U + I;
    int E = in_sizes[9] / R;
    int Bn = in_sizes[0];
    int NR = N * R;
    int Etot = E * R;
    int SLICE_N = (N + 7) / 8;

    char* p = (char*)d_ws;
    auto carve = [&](size_t bytes) -> char* {
        char* q = p;
        p += (bytes + 255) & ~(size_t)255;
        return q;
    };
    float* out_acc = (float*)carve((size_t)N * 64 * 4);
    float* bufA = (float*)carve((size_t)N * 64 * 4);
    float* bufB = (float*)carve((size_t)N * 64 * 4);
    uint2* rec = (uint2*)carve((size_t)E * 8);
    int* row_ptr = (int*)carve((size_t)(NR + 1) * 4);
    int* cnt = (int*)carve((size_t)NR * 4);
    int* bsums = (int*)carve(4096);
    float* c1_all = (float*)carve((size_t)R * 64 * 4);
    unsigned char* flag = (unsigned char*)carve((size_t)N);
    int* flist = (int*)carve((size_t)2 * Bn * 4);
    int* fcount = (int*)carve(4);

    uint64_t maskbits = compute_mask_bits();

    hipMemsetAsync(out_acc, 0, (size_t)N * 64 * 4, stream);
    hipMemsetAsync(flag, 0, (size_t)N, stream);
    hipMemsetAsync(fcount, 0, 4, stream);
    hipMemsetAsync(cnt, 0, (size_t)NR * 4, stream);

    flag_kernel<<<(2 * Bn + 255) / 256, 256, 0, stream>>>(users, items, flag, Bn, U);
    flist_kernel<<<(N + 255) / 256, 256, 0, stream>>>(flag, flist, fcount, N);
    c1_kernel<<<R, 64, 0, stream>>>(rating_emb, W1, b1, c1_all);

    // XCD-sliced batched histogram + scans over all ratings
    int echunks = (E + 255) / 256;
    dim3 hgrid(8 * echunks, R);
    hist_all_kernel<<<hgrid, 256, 0, stream>>>(rows, cnt, E, N, SLICE_N);
    int NB1 = (NR + 1023) / 1024;
    scan1_kernel<<<NB1, 256, 0, stream>>>(cnt, row_ptr, bsums, NR);
    scan2_kernel<<<1, 256, 0, stream>>>(bsums, NB1);
    scan3_kernel<<<(NR + 255) / 256, 256, 0, stream>>>(row_ptr, bsums, NR, Etot);

    int spmm_blocks = 8 * ((N + 3) / 4);
    int masked_blocks = 8 * ((2 * Bn + 3) / 4);
    for (int r = 0; r < R; r++) {
        const int* rows_r = rows + (size_t)r * E;
        const int* cols_r = cols + (size_t)r * E;
        const float* vals_r = vals + (size_t)r * E;
        const int* rp_r = row_ptr + (size_t)r * N;
        int* cnt_r = cnt + (size_t)r * N;
        int ebase = r * E;

        scatter_kernel<<<8 * echunks, 256, 0, stream>>>(rows_r, cols_r, vals_r, rp_r,
                                                        cnt_r, rec, E, ebase, SLICE_N);

        mlp_kernel<<<(N + 63) / 64, 256, 0, stream>>>(user_emb, item_emb, W1, W2,
                                                      c1_all, b2, bufA, out_acc,
                                                      flag, r, N, U);

        spmm_kernel<<<spmm_blocks, 256, 0, stream>>>(bufA, bufB, out_acc, rp_r,
                                                     rec, flag, N, ebase);
        spmm_kernel<<<spmm_blocks, 256, 0, stream>>>(bufB, bufA, out_acc, rp_r,
                                                     rec, flag, N, ebase);
        spmm_masked_kernel<<<masked_blocks, 256, 0, stream>>>(bufA, out_acc, rp_r,
                                                              rec, maskbits,
                                                              flist, fcount, ebase);
    }

    float scale = 1.0f / (float)(R * R);
    dot_kernel<<<(Bn * 64 + 255) / 256, 256, 0, stream>>>(out_acc, users, items, out,
                                                          Bn, U, scale);
}

// Round 9
// 1297.441 us; speedup vs baseline: 3.2961x; 3.2961x over previous
//
#include <hip/hip_runtime.h>
#include <hip/hip_bf16.h>
#include <cstdint>
#include <cstddef>

// ---------------------------------------------------------------------------
// Host-side reproduction of np.random.RandomState(2).permutation(64):
// MT19937 init_genrand(2), Fisher-Yates with numpy random_interval
// (mask+rejection). Mask bit d = (perm[d] >= 38).
// ---------------------------------------------------------------------------
static uint64_t compute_mask_bits() {
    uint32_t mt[624];
    mt[0] = 2u;
    for (int i = 1; i < 624; i++)
        mt[i] = 1812433253u * (mt[i - 1] ^ (mt[i - 1] >> 30)) + (uint32_t)i;
    int mti = 624;
    auto genrand = [&]() -> uint32_t {
        if (mti >= 624) {
            for (int k = 0; k < 624; k++) {
                uint32_t y = (mt[k] & 0x80000000u) | (mt[(k + 1) % 624] & 0x7fffffffu);
                mt[k] = mt[(k + 397) % 624] ^ (y >> 1) ^ ((y & 1u) ? 2567483615u : 0u);
            }
            mti = 0;
        }
        uint32_t y = mt[mti++];
        y ^= y >> 11;
        y ^= (y << 7) & 2636928640u;
        y ^= (y << 15) & 4022730752u;
        y ^= y >> 18;
        return y;
    };
    int arr[64];
    for (int i = 0; i < 64; i++) arr[i] = i;
    for (int i = 63; i >= 1; i--) {
        uint32_t mask = (uint32_t)i;
        mask |= mask >> 1; mask |= mask >> 2; mask |= mask >> 4;
        mask |= mask >> 8; mask |= mask >> 16;
        uint32_t v;
        do { v = genrand() & mask; } while (v > (uint32_t)i);
        int tmp = arr[i]; arr[i] = arr[v]; arr[v] = tmp;
    }
    uint64_t bits = 0;
    for (int d = 0; d < 64; d++)
        if (arr[d] >= 38) bits |= (1ull << d);
    return bits;
}

// ---------------------------------------------------------------------------
// Output-row flag set + compacted list (rows read by the final dot).
// ---------------------------------------------------------------------------
__global__ void flag_kernel(const int* __restrict__ users, const int* __restrict__ items,
                            unsigned char* __restrict__ flag, int B, int U) {
    int i = blockIdx.x * 256 + threadIdx.x;
    if (i < B) flag[users[i]] = 1;
    else if (i < 2 * B) flag[U + items[i - B]] = 1;
}

__global__ void flist_kernel(const unsigned char* __restrict__ flag,
                             int* __restrict__ flist, int* __restrict__ fcount, int n) {
    int i = blockIdx.x * 256 + threadIdx.x;
    if (i < n && flag[i]) {
        int p = atomicAdd(fcount, 1);
        flist[p] = i;
    }
}

// ---------------------------------------------------------------------------
// Per-rating constant c1[r][j] = b1[r][j] + sum_k e_r[k] * W1[r][64+k][j].
// ---------------------------------------------------------------------------
__global__ void c1_kernel(const float* __restrict__ rating_emb, const float* __restrict__ W1,
                          const float* __restrict__ b1, float* __restrict__ c1_all) {
    int r = blockIdx.x;
    int t = threadIdx.x;  // 64 threads
    const float* W1r = W1 + (size_t)r * (128 * 64);
    float acc = b1[r * 64 + t];
    for (int k = 0; k < 64; k++)
        acc += rating_emb[r * 64 + k] * W1r[(64 + k) * 64 + t];
    c1_all[r * 64 + t] = acc;
}

// ---------------------------------------------------------------------------
// XCD-sliced batched histogram: slice = blockIdx.x & 7 (round-robin XCD
// heuristic), rating = blockIdx.y. Each block reads its whole edge chunk but
// counts only rows in its 1/8 row slice -> cnt lines stay in one XCD's L2.
// ---------------------------------------------------------------------------
__global__ void hist_all_kernel(const int* __restrict__ rows, int* __restrict__ cnt,
                                int E, int N, int SLICE_N) {
    int r = blockIdx.y;
    int slice = blockIdx.x & 7;
    int i = (blockIdx.x >> 3) * 256 + threadIdx.x;
    if (i >= E) return;
    int row = rows[(size_t)r * E + i];
    int lo = slice * SLICE_N;
    if (row < lo || row >= lo + SLICE_N) return;
    atomicAdd(&cnt[(size_t)r * N + row], 1);
}

__global__ void scan1_kernel(const int* __restrict__ cnt, int* __restrict__ rp,
                             int* __restrict__ bsums, int n) {
    __shared__ int sh[256];
    int t = threadIdx.x;
    int base = blockIdx.x * 1024 + t * 4;
    int v0 = 0, v1 = 0, v2 = 0, v3 = 0;
    if (base + 3 < n) {
        int4 q = *(const int4*)(cnt + base);
        v0 = q.x; v1 = q.y; v2 = q.z; v3 = q.w;
    } else {
        if (base + 0 < n) v0 = cnt[base + 0];
        if (base + 1 < n) v1 = cnt[base + 1];
        if (base + 2 < n) v2 = cnt[base + 2];
        if (base + 3 < n) v3 = cnt[base + 3];
    }
    int total = v0 + v1 + v2 + v3;
    sh[t] = total;
    __syncthreads();
    for (int off = 1; off < 256; off <<= 1) {
        int x = (t >= off) ? sh[t - off] : 0;
        __syncthreads();
        sh[t] += x;
        __syncthreads();
    }
    int excl = sh[t] - total;
    if (base + 0 < n) rp[base + 0] = excl;
    if (base + 1 < n) rp[base + 1] = excl + v0;
    if (base + 2 < n) rp[base + 2] = excl + v0 + v1;
    if (base + 3 < n) rp[base + 3] = excl + v0 + v1 + v2;
    if (t == 255) bsums[blockIdx.x] = sh[255];
}

__global__ void scan2_kernel(int* __restrict__ bsums, int nb) {
    __shared__ int sh[256];
    int t = threadIdx.x;
    int base = t * 4;
    int v[4]; int s = 0;
    #pragma unroll
    for (int j = 0; j < 4; j++) {
        v[j] = (base + j < nb) ? bsums[base + j] : 0;
        s += v[j];
    }
    sh[t] = s;
    __syncthreads();
    for (int off = 1; off < 256; off <<= 1) {
        int x = (t >= off) ? sh[t - off] : 0;
        __syncthreads();
        sh[t] += x;
        __syncthreads();
    }
    int run = sh[t] - s;
    #pragma unroll
    for (int j = 0; j < 4; j++) {
        if (base + j < nb) bsums[base + j] = run;
        run += v[j];
    }
}

__global__ void scan3_kernel(int* __restrict__ rp, const int* __restrict__ bsums,
                             int n, int e_total) {
    int i = blockIdx.x * 256 + threadIdx.x;
    if (i < n) rp[i] += bsums[i >> 10];
    if (i == 0) rp[n] = e_total;
}

// ---------------------------------------------------------------------------
// XCD-sliced scatter: rank recovered from atomicSub(cnt) (slice-local lines);
// rec positions for one row-slice are contiguous (CSR is row-ordered), so
// stores never share lines across XCDs. Per-rating launch; rec stays E-sized.
// ---------------------------------------------------------------------------
__global__ void scatter_kernel(const int* __restrict__ rows, const int* __restrict__ cols,
                               const float* __restrict__ vals, const int* __restrict__ rp,
                               int* __restrict__ cnt_r, uint2* __restrict__ rec,
                               int E, int ebase, int SLICE_N) {
    int slice = blockIdx.x & 7;
    int i = (blockIdx.x >> 3) * 256 + threadIdx.x;
    if (i >= E) return;
    int row = rows[i];
    int lo = slice * SLICE_N;
    if (row < lo || row >= lo + SLICE_N) return;
    int old = atomicSub(&cnt_r[row], 1);
    int pos = rp[row] - ebase + old - 1;
    rec[pos] = make_uint2((uint32_t)cols[i], __float_as_uint(vals[i]));
}

// ---------------------------------------------------------------------------
// Per-rating MLP: h = leaky_relu(x @ W1a + c1) @ W2 + b2
// LDS: one W tile + one X/T tile (reused) = 33 KB; 16B-group XOR swizzle
// keeps all LDS streams conflict-free. prev = h; out_acc += h (flagged).
// ---------------------------------------------------------------------------
__global__ __launch_bounds__(256) void mlp_kernel(
    const float* __restrict__ user_emb, const float* __restrict__ item_emb,
    const float* __restrict__ W1, const float* __restrict__ W2,
    const float* __restrict__ c1_all, const float* __restrict__ b2,
    float* __restrict__ prev, float* __restrict__ out_acc,
    const unsigned char* __restrict__ flag, int r, int n_rows, int U) {
    __shared__ float sW[64 * 64];   // [k][j], linear
    __shared__ float sX[64 * 64];   // [k][i], group-swizzled; reused for T
    __shared__ float sc1[64];
    __shared__ float sb2v[64];

    int t = threadIdx.x;
    int row0 = blockIdx.x * 64;
    const float* W1r = W1 + (size_t)r * (128 * 64);
    const float* W2r = W2 + (size_t)r * (64 * 64);

    #pragma unroll
    for (int q = 0; q < 4; q++) {
        int f = t + 256 * q;
        int k = f >> 4, c = (f & 15) * 4;
        *(float4*)(sW + k * 64 + c) = *(const float4*)(W1r + k * 64 + c);
    }
    #pragma unroll
    for (int q = 0; q < 4; q++) {
        int f = t + 256 * q;
        int i = f & 63;
        int c = (f >> 6) * 4;
        int nrow = row0 + i;
        float4 xv = make_float4(0.f, 0.f, 0.f, 0.f);
        if (nrow < n_rows) {
            const float* src = (nrow < U) ? (user_emb + (size_t)nrow * 64)
                                          : (item_emb + (size_t)(nrow - U) * 64);
            xv = *(const float4*)(src + c);
        }
        int gi = i >> 2, w = i & 3;
        sX[(c + 0) * 64 + 4 * (gi ^ ((c + 0) & 15)) + w] = xv.x;
        sX[(c + 1) * 64 + 4 * (gi ^ ((c + 1) & 15)) + w] = xv.y;
        sX[(c + 2) * 64 + 4 * (gi ^ ((c + 2) & 15)) + w] = xv.z;
        sX[(c + 3) * 64 + 4 * (gi ^ ((c + 3) & 15)) + w] = xv.w;
    }
    if (t < 64) sc1[t] = c1_all[r * 64 + t];
    else if (t < 128) sb2v[t - 64] = b2[r * 64 + (t - 64)];
    __syncthreads();

    int gi = t & 15;
    int i0 = gi * 4, j0 = (t >> 4) * 4;
    float acc[4][4];
    #pragma unroll
    for (int a = 0; a < 4; a++)
        #pragma unroll
        for (int b = 0; b < 4; b++) acc[a][b] = sc1[j0 + b];
    for (int k = 0; k < 64; k++) {
        float4 xv = *(const float4*)(sX + k * 64 + 4 * (gi ^ (k & 15)));
        float4 wv = *(const float4*)(sW + k * 64 + j0);
        float xs[4] = {xv.x, xv.y, xv.z, xv.w};
        float ws[4] = {wv.x, wv.y, wv.z, wv.w};
        #pragma unroll
        for (int a = 0; a < 4; a++)
            #pragma unroll
            for (int b = 0; b < 4; b++) acc[a][b] += xs[a] * ws[b];
    }
    __syncthreads();

    #pragma unroll
    for (int b = 0; b < 4; b++) {
        int k = j0 + b;
        float4 tv;
        tv.x = (acc[0][b] >= 0.f) ? acc[0][b] : 0.01f * acc[0][b];
        tv.y = (acc[1][b] >= 0.f) ? acc[1][b] : 0.01f * acc[1][b];
        tv.z = (acc[2][b] >= 0.f) ? acc[2][b] : 0.01f * acc[2][b];
        tv.w = (acc[3][b] >= 0.f) ? acc[3][b] : 0.01f * acc[3][b];
        *(float4*)(sX + k * 64 + 4 * (gi ^ (k & 15))) = tv;
    }
    #pragma unroll
    for (int q = 0; q < 4; q++) {
        int f = t + 256 * q;
        int k = f >> 4, c = (f & 15) * 4;
        *(float4*)(sW + k * 64 + c) = *(const float4*)(W2r + k * 64 + c);
    }
    __syncthreads();

    #pragma unroll
    for (int a = 0; a < 4; a++)
        #pragma unroll
        for (int b = 0; b < 4; b++) acc[a][b] = sb2v[j0 + b];
    for (int k = 0; k < 64; k++) {
        float4 xv = *(const float4*)(sX + k * 64 + 4 * (gi ^ (k & 15)));
        float4 wv = *(const float4*)(sW + k * 64 + j0);
        float xs[4] = {xv.x, xv.y, xv.z, xv.w};
        float ws[4] = {wv.x, wv.y, wv.z, wv.w};
        #pragma unroll
        for (int a = 0; a < 4; a++)
            #pragma unroll
            for (int b = 0; b < 4; b++) acc[a][b] += xs[a] * ws[b];
    }
    #pragma unroll
    for (int a = 0; a < 4; a++) {
        int nrow = row0 + i0 + a;
        if (nrow < n_rows) {
            float4 hv = make_float4(acc[a][0], acc[a][1], acc[a][2], acc[a][3]);
            *(float4*)(prev + (size_t)nrow * 64 + j0) = hv;
            if (flag[nrow]) {
                float4 ov = *(const float4*)(out_acc + (size_t)nrow * 64 + j0);
                ov.x += hv.x; ov.y += hv.y; ov.z += hv.z; ov.w += hv.w;
                *(float4*)(out_acc + (size_t)nrow * 64 + j0) = ov;
            }
        }
    }
}

// ---------------------------------------------------------------------------
// Gather-SpMM (layers 0/1): wave = 1 row; 4 edge-groups x 16 lanes x float4
// (full 256B row consumed per gather -> no fetch waste). 8 edges in flight.
// rp pre-offset by r*N; positions rebased by ebase = r*E.
// ---------------------------------------------------------------------------
__global__ __launch_bounds__(256) void spmm_kernel(
    const float* __restrict__ prev, float* __restrict__ next,
    float* __restrict__ out_acc, const int* __restrict__ rp,
    const uint2* __restrict__ rec, const unsigned char* __restrict__ flag,
    int n, int ebase) {
    int wave = (int)((blockIdx.x * (unsigned)blockDim.x + threadIdx.x) >> 6);
    int lane = threadIdx.x & 63;
    if (wave >= n) return;
    int sub = lane >> 4;      // edge group 0..3
    int dl = lane & 15;       // dims [dl*4, dl*4+4)
    int s = rp[wave] - ebase, e2 = rp[wave + 1] - ebase;
    float ax = 0.f, ay = 0.f, az = 0.f, aw = 0.f;
    int e = s + sub;
    for (; e + 4 < e2; e += 8) {
        uint2 r0 = rec[e];
        uint2 r1 = rec[e + 4];
        float4 p0 = *(const float4*)(prev + (size_t)r0.x * 64 + dl * 4);
        float4 p1 = *(const float4*)(prev + (size_t)r1.x * 64 + dl * 4);
        float v0 = __uint_as_float(r0.y), v1 = __uint_as_float(r1.y);
        ax += v0 * p0.x; ay += v0 * p0.y; az += v0 * p0.z; aw += v0 * p0.w;
        ax += v1 * p1.x; ay += v1 * p1.y; az += v1 * p1.z; aw += v1 * p1.w;
    }
    if (e < e2) {
        uint2 r0 = rec[e];
        float4 p0 = *(const float4*)(prev + (size_t)r0.x * 64 + dl * 4);
        float v0 = __uint_as_float(r0.y);
        ax += v0 * p0.x; ay += v0 * p0.y; az += v0 * p0.z; aw += v0 * p0.w;
    }
    ax += __shfl_xor(ax, 16); ay += __shfl_xor(ay, 16);
    az += __shfl_xor(az, 16); aw += __shfl_xor(aw, 16);
    ax += __shfl_xor(ax, 32); ay += __shfl_xor(ay, 32);
    az += __shfl_xor(az, 32); aw += __shfl_xor(aw, 32);
    if (sub == 0) {
        *(float4*)(next + (size_t)wave * 64 + dl * 4) = make_float4(ax, ay, az, aw);
    } else if (sub == 1 && flag[wave]) {
        float* o = out_acc + (size_t)wave * 64 + dl * 4;
        float4 ov = *(const float4*)o;
        ov.x += ax; ov.y += ay; ov.z += az; ov.w += aw;
        *(float4*)o = ov;
    }
}

// ---------------------------------------------------------------------------
// Layer-2 (masked) SpMM: only rows in flist. Same float4-lane layout.
// ---------------------------------------------------------------------------
__global__ __launch_bounds__(256) void spmm_masked_kernel(
    const float* __restrict__ prev, float* __restrict__ out_acc,
    const int* __restrict__ rp, const uint2* __restrict__ rec,
    unsigned long long maskbits, const int* __restrict__ flist,
    const int* __restrict__ fcount, int ebase) {
    int w = (int)((blockIdx.x * (unsigned)blockDim.x + threadIdx.x) >> 6);
    int lane = threadIdx.x & 63;
    if (w >= *fcount) return;
    int sub = lane >> 4;
    int dl = lane & 15;
    int row = flist[w];
    int s = rp[row] - ebase, e2 = rp[row + 1] - ebase;
    float ax = 0.f, ay = 0.f, az = 0.f, aw = 0.f;
    int e = s + sub;
    for (; e + 4 < e2; e += 8) {
        uint2 r0 = rec[e];
        uint2 r1 = rec[e + 4];
        float4 p0 = *(const float4*)(prev + (size_t)r0.x * 64 + dl * 4);
        float4 p1 = *(const float4*)(prev + (size_t)r1.x * 64 + dl * 4);
        float v0 = __uint_as_float(r0.y), v1 = __uint_as_float(r1.y);
        ax += v0 * p0.x; ay += v0 * p0.y; az += v0 * p0.z; aw += v0 * p0.w;
        ax += v1 * p1.x; ay += v1 * p1.y; az += v1 * p1.z; aw += v1 * p1.w;
    }
    if (e < e2) {
        uint2 r0 = rec[e];
        float4 p0 = *(const float4*)(prev + (size_t)r0.x * 64 + dl * 4);
        float v0 = __uint_as_float(r0.y);
        ax += v0 * p0.x; ay += v0 * p0.y; az += v0 * p0.z; aw += v0 * p0.w;
    }
    ax += __shfl_xor(ax, 16); ay += __shfl_xor(ay, 16);
    az += __shfl_xor(az, 16); aw += __shfl_xor(aw, 16);
    ax += __shfl_xor(ax, 32); ay += __shfl_xor(ay, 32);
    az += __shfl_xor(az, 32); aw += __shfl_xor(aw, 32);
    if (sub == 0) {
        const float* pv = prev + (size_t)row * 64 + dl * 4;
        float4 pvv = *(const float4*)pv;
        float rx = ((maskbits >> (dl * 4 + 0)) & 1ull) ? ax : pvv.x;
        float ry = ((maskbits >> (dl * 4 + 1)) & 1ull) ? ay : pvv.y;
        float rz = ((maskbits >> (dl * 4 + 2)) & 1ull) ? az : pvv.z;
        float rw = ((maskbits >> (dl * 4 + 3)) & 1ull) ? aw : pvv.w;
        float* o = out_acc + (size_t)row * 64 + dl * 4;
        float4 ov = *(const float4*)o;
        ov.x += rx; ov.y += ry; ov.z += rz; ov.w += rw;
        *(float4*)o = ov;
    }
}

// ---------------------------------------------------------------------------
// Final: out[b] = (1/R^2) * dot(out_acc[users[b]], out_acc[U+items[b]])
// ---------------------------------------------------------------------------
__global__ __launch_bounds__(256) void dot_kernel(
    const float* __restrict__ out_acc, const int* __restrict__ users,
    const int* __restrict__ items, float* __restrict__ out,
    int Bn, int U, float scale) {
    int w = (int)((blockIdx.x * (unsigned)blockDim.x + threadIdx.x) >> 6);
    int lane = threadIdx.x & 63;
    if (w >= Bn) return;
    int u = users[w], it = items[w];
    float a = out_acc[(size_t)u * 64 + lane];
    float c = out_acc[((size_t)(U + it)) * 64 + lane];
    float p = a * c;
    #pragma unroll
    for (int off = 32; off > 0; off >>= 1) p += __shfl_down(p, off);
    if (lane == 0) out[w] = p * scale;
}

// ---------------------------------------------------------------------------
extern "C" void kernel_launch(void* const* d_in, const int* in_sizes, int n_in,
                              void* d_out, int out_size, void* d_ws, size_t ws_size,
                              hipStream_t stream) {
    const int* users = (const int*)d_in[0];
    const int* items = (const int*)d_in[1];
    const float* user_emb = (const float*)d_in[2];
    const float* item_emb = (const float*)d_in[3];
    const float* rating_emb = (const float*)d_in[4];
    const float* W1 = (const float*)d_in[5];
    const float* b1 = (const float*)d_in[6];
    const float* W2 = (const float*)d_in[7];
    const float* b2 = (const float*)d_in[8];
    const int* rows = (const int*)d_in[9];
    const int* cols = (const int*)d_in[10];
    const float* vals = (const float*)d_in[11];
    float* out = (float*)d_out;

    const int Dd = 64;
    int U = in_sizes[2] / Dd;
    int I = in_sizes[3] / Dd;
    int R = in_sizes[4] / Dd;
    int N = U + I;
    int E = in_sizes[9] / R;
    int Bn = in_sizes[0];
    int NR = N * R;
    int Etot = E * R;
    int SLICE_N = (N + 7) / 8;

    char* p = (char*)d_ws;
    auto carve = [&](size_t bytes) -> char* {
        char* q = p;
        p += (bytes + 255) & ~(size_t)255;
        return q;
    };
    float* out_acc = (float*)carve((size_t)N * 64 * 4);
    float* bufA = (float*)carve((size_t)N * 64 * 4);
    float* bufB = (float*)carve((size_t)N * 64 * 4);
    uint2* rec = (uint2*)carve((size_t)E * 8);
    int* row_ptr = (int*)carve((size_t)(NR + 1) * 4);
    int* cnt = (int*)carve((size_t)NR * 4);
    int* bsums = (int*)carve(4096);
    float* c1_all = (float*)carve((size_t)R * 64 * 4);
    unsigned char* flag = (unsigned char*)carve((size_t)N);
    int* flist = (int*)carve((size_t)2 * Bn * 4);
    int* fcount = (int*)carve(4);

    uint64_t maskbits = compute_mask_bits();

    hipMemsetAsync(out_acc, 0, (size_t)N * 64 * 4, stream);
    hipMemsetAsync(flag, 0, (size_t)N, stream);
    hipMemsetAsync(fcount, 0, 4, stream);
    hipMemsetAsync(cnt, 0, (size_t)NR * 4, stream);

    flag_kernel<<<(2 * Bn + 255) / 256, 256, 0, stream>>>(users, items, flag, Bn, U);
    flist_kernel<<<(N + 255) / 256, 256, 0, stream>>>(flag, flist, fcount, N);
    c1_kernel<<<R, 64, 0, stream>>>(rating_emb, W1, b1, c1_all);

    // XCD-sliced batched histogram + scans over all ratings
    int echunks = (E + 255) / 256;
    dim3 hgrid(8 * echunks, R);
    hist_all_kernel<<<hgrid, 256, 0, stream>>>(rows, cnt, E, N, SLICE_N);
    int NB1 = (NR + 1023) / 1024;
    scan1_kernel<<<NB1, 256, 0, stream>>>(cnt, row_ptr, bsums, NR);
    scan2_kernel<<<1, 256, 0, stream>>>(bsums, NB1);
    scan3_kernel<<<(NR + 255) / 256, 256, 0, stream>>>(row_ptr, bsums, NR, Etot);

    int spmm_blocks = (N + 3) / 4;
    int masked_blocks = (2 * Bn + 3) / 4;
    for (int r = 0; r < R; r++) {
        const int* rows_r = rows + (size_t)r * E;
        const int* cols_r = cols + (size_t)r * E;
        const float* vals_r = vals + (size_t)r * E;
        const int* rp_r = row_ptr + (size_t)r * N;
        int* cnt_r = cnt + (size_t)r * N;
        int ebase = r * E;

        scatter_kernel<<<8 * echunks, 256, 0, stream>>>(rows_r, cols_r, vals_r, rp_r,
                                                        cnt_r, rec, E, ebase, SLICE_N);

        mlp_kernel<<<(N + 63) / 64, 256, 0, stream>>>(user_emb, item_emb, W1, W2,
                                                      c1_all, b2, bufA, out_acc,
                                                      flag, r, N, U);

        spmm_kernel<<<spmm_blocks, 256, 0, stream>>>(bufA, bufB, out_acc, rp_r,
                                                     rec, flag, N, ebase);
        spmm_kernel<<<spmm_blocks, 256, 0, stream>>>(bufB, bufA, out_acc, rp_r,
                                                     rec, flag, N, ebase);
        spmm_masked_kernel<<<masked_blocks, 256, 0, stream>>>(bufA, out_acc, rp_r,
                                                              rec, maskbits,
                                                              flist, fcount, ebase);
    }

    float scale = 1.0f / (float)(R * R);
    dot_kernel<<<(Bn * 64 + 255) / 256, 256, 0, stream>>>(out_acc, users, items, out,
                                                          Bn, U, scale);
}

// Round 10
// 1080.876 us; speedup vs baseline: 3.9565x; 1.2004x over previous
//
#include <hip/hip_runtime.h>
#include <hip/hip_bf16.h>
#include <cstdint>
#include <cstddef>

#define KEYSHIFT 20
#define COLMASK 0xFFFFFu
#define EPB 16384   // edges per count/scatter block (1024 threads x 16)

// ---------------------------------------------------------------------------
// Host-side reproduction of np.random.RandomState(2).permutation(64):
// MT19937 init_genrand(2), Fisher-Yates with numpy random_interval
// (mask+rejection). Mask bit d = (perm[d] >= 38).
// ---------------------------------------------------------------------------
static uint64_t compute_mask_bits() {
    uint32_t mt[624];
    mt[0] = 2u;
    for (int i = 1; i < 624; i++)
        mt[i] = 1812433253u * (mt[i - 1] ^ (mt[i - 1] >> 30)) + (uint32_t)i;
    int mti = 624;
    auto genrand = [&]() -> uint32_t {
        if (mti >= 624) {
            for (int k = 0; k < 624; k++) {
                uint32_t y = (mt[k] & 0x80000000u) | (mt[(k + 1) % 624] & 0x7fffffffu);
                mt[k] = mt[(k + 397) % 624] ^ (y >> 1) ^ ((y & 1u) ? 2567483615u : 0u);
            }
            mti = 0;
        }
        uint32_t y = mt[mti++];
        y ^= y >> 11;
        y ^= (y << 7) & 2636928640u;
        y ^= (y << 15) & 4022730752u;
        y ^= y >> 18;
        return y;
    };
    int arr[64];
    for (int i = 0; i < 64; i++) arr[i] = i;
    for (int i = 63; i >= 1; i--) {
        uint32_t mask = (uint32_t)i;
        mask |= mask >> 1; mask |= mask >> 2; mask |= mask >> 4;
        mask |= mask >> 8; mask |= mask >> 16;
        uint32_t v;
        do { v = genrand() & mask; } while (v > (uint32_t)i);
        int tmp = arr[i]; arr[i] = arr[v]; arr[v] = tmp;
    }
    uint64_t bits = 0;
    for (int d = 0; d < 64; d++)
        if (arr[d] >= 38) bits |= (1ull << d);
    return bits;
}

// ---------------------------------------------------------------------------
// Output-row flag set + compacted list (rows read by the final dot).
// ---------------------------------------------------------------------------
__global__ void flag_kernel(const int* __restrict__ users, const int* __restrict__ items,
                            unsigned char* __restrict__ flag, int B, int U) {
    int i = blockIdx.x * 256 + threadIdx.x;
    if (i < B) flag[users[i]] = 1;
    else if (i < 2 * B) flag[U + items[i - B]] = 1;
}

__global__ void flist_kernel(const unsigned char* __restrict__ flag,
                             int* __restrict__ flist, int* __restrict__ fcount, int n) {
    int i = blockIdx.x * 256 + threadIdx.x;
    if (i < n && flag[i]) {
        int p = atomicAdd(fcount, 1);
        flist[p] = i;
    }
}

// ---------------------------------------------------------------------------
// Per-rating constant c1[r][j] = b1[r][j] + sum_k e_r[k] * W1[r][64+k][j].
// ---------------------------------------------------------------------------
__global__ void c1_kernel(const float* __restrict__ rating_emb, const float* __restrict__ W1,
                          const float* __restrict__ b1, float* __restrict__ c1_all) {
    int r = blockIdx.x;
    int t = threadIdx.x;  // 64 threads
    const float* W1r = W1 + (size_t)r * (128 * 64);
    float acc = b1[r * 64 + t];
    for (int k = 0; k < 64; k++)
        acc += rating_emb[r * 64 + k] * W1r[(64 + k) * 64 + t];
    c1_all[r * 64 + t] = acc;
}

// ---------------------------------------------------------------------------
// Build pass A (batched over ratings): LDS histogram over K=ceil(N/64) row
// buckets, then ONE global atomicAdd per (block,bucket) to reserve a range.
// Reduces global atomics ~10x vs per-edge hist (the 32B-per-atomic
// write-through made per-edge hist cost ~200us).
// ---------------------------------------------------------------------------
__global__ __launch_bounds__(1024) void bucket_count_kernel(
    const int* __restrict__ rows, int* __restrict__ gcnt,
    int* __restrict__ blockBase, int E, int K, int nb) {
    __shared__ int hist[2048];
    int r = blockIdx.y, blk = blockIdx.x, t = threadIdx.x;
    for (int i = t; i < K; i += 1024) hist[i] = 0;
    __syncthreads();
    size_t base = (size_t)r * E + (size_t)blk * EPB;
    int cnt = E - blk * EPB;
    if (cnt > EPB) cnt = EPB;
    for (int k = t; k < cnt; k += 1024)
        atomicAdd(&hist[rows[base + k] >> 6], 1);
    __syncthreads();
    for (int i = t; i < K; i += 1024) {
        int c = hist[i];
        int bb = (c > 0) ? atomicAdd(&gcnt[r * K + i], c) : 0;
        blockBase[((size_t)r * nb + blk) * K + i] = bb;
    }
}

// ---------------------------------------------------------------------------
// Exclusive scan of K bucket counts -> bptr[K+1] per rating (grid.x = R).
// 256 threads x 8/thread covers K+1 <= 2048.
// ---------------------------------------------------------------------------
__global__ void bucket_scan_kernel(const int* __restrict__ gcnt,
                                   int* __restrict__ bptr, int K) {
    __shared__ int sh[256];
    int r = blockIdx.x;
    int t = threadIdx.x;
    int base = t * 8;
    int v[8];
    int s = 0;
    #pragma unroll
    for (int j = 0; j < 8; j++) {
        int idx = base + j;
        v[j] = (idx < K) ? gcnt[r * K + idx] : 0;
        s += v[j];
    }
    sh[t] = s;
    __syncthreads();
    for (int off = 1; off < 256; off <<= 1) {
        int x = (t >= off) ? sh[t - off] : 0;
        __syncthreads();
        sh[t] += x;
        __syncthreads();
    }
    int run = sh[t] - s;
    #pragma unroll
    for (int j = 0; j < 8; j++) {
        int idx = base + j;
        if (idx <= K) bptr[r * (K + 1) + idx] = run;
        run += v[j];
    }
}

// ---------------------------------------------------------------------------
// Build pass B (per rating): atomic-free scatter into bucket-grouped rec.
// Position = bptr[bucket] + blockBase[blk][bucket] + LDS-cursor rank.
// Record: (rel<<20 | col, val).
// ---------------------------------------------------------------------------
__global__ __launch_bounds__(1024) void bucket_scatter_kernel(
    const int* __restrict__ rows, const int* __restrict__ cols,
    const float* __restrict__ vals, const int* __restrict__ bptr_r,
    const int* __restrict__ blockBase_r, uint2* __restrict__ rec,
    int E, int K, int nb) {
    __shared__ int cursor[2048];
    int blk = blockIdx.x, t = threadIdx.x;
    for (int i = t; i < K; i += 1024)
        cursor[i] = bptr_r[i] + blockBase_r[(size_t)blk * K + i];
    __syncthreads();
    size_t base = (size_t)blk * EPB;
    int cnt = E - blk * EPB;
    if (cnt > EPB) cnt = EPB;
    for (int k = t; k < cnt; k += 1024) {
        int row = rows[base + k];
        int b = row >> 6;
        int pos = atomicAdd(&cursor[b], 1);
        uint32_t key = ((uint32_t)(row & 63) << KEYSHIFT) | (uint32_t)cols[base + k];
        rec[pos] = make_uint2(key, __float_as_uint(vals[base + k]));
    }
}

// ---------------------------------------------------------------------------
// Build pass C (per rating): per-bucket counting sort by rel-row (validated
// in R4): rec -> srec row-sorted; emits row_ptr (rating-local offsets).
// ---------------------------------------------------------------------------
__global__ __launch_bounds__(256) void bucket_sort_kernel(
    const uint2* __restrict__ rec, uint2* __restrict__ srec,
    const int* __restrict__ bptr_r, int* __restrict__ rp_r, int K, int N) {
    __shared__ int hist[64];
    __shared__ int excl[64];
    int b = blockIdx.x;
    int t = threadIdx.x;
    if (t < 64) hist[t] = 0;
    __syncthreads();
    int start = bptr_r[b], end = bptr_r[b + 1];
    for (int e = start + t; e < end; e += 256) {
        uint2 r = rec[e];
        atomicAdd(&hist[r.x >> KEYSHIFT], 1);
    }
    __syncthreads();
    if (t == 0) {
        int run = 0;
        #pragma unroll
        for (int i = 0; i < 64; i++) { excl[i] = run; run += hist[i]; }
    }
    __syncthreads();
    if (t < 64) {
        int row = b * 64 + t;
        if (row < N) rp_r[row] = start + excl[t];
        hist[t] = 0;  // reuse as cursors
    }
    if (b == K - 1 && t == 0) rp_r[N] = bptr_r[K];
    __syncthreads();
    for (int e = start + t; e < end; e += 256) {
        uint2 r = rec[e];
        int rel = (int)(r.x >> KEYSHIFT);
        int pos = start + excl[rel] + atomicAdd(&hist[rel], 1);
        srec[pos] = r;
    }
}

// ---------------------------------------------------------------------------
// Per-rating MLP: h = leaky_relu(x @ W1a + c1) @ W2 + b2
// LDS: one W tile + one X/T tile (reused) = 33 KB; 16B-group XOR swizzle
// keeps all LDS streams conflict-free. prev = h; out_acc += h (flagged).
// ---------------------------------------------------------------------------
__global__ __launch_bounds__(256) void mlp_kernel(
    const float* __restrict__ user_emb, const float* __restrict__ item_emb,
    const float* __restrict__ W1, const float* __restrict__ W2,
    const float* __restrict__ c1_all, const float* __restrict__ b2,
    float* __restrict__ prev, float* __restrict__ out_acc,
    const unsigned char* __restrict__ flag, int r, int n_rows, int U) {
    __shared__ float sW[64 * 64];   // [k][j], linear
    __shared__ float sX[64 * 64];   // [k][i], group-swizzled; reused for T
    __shared__ float sc1[64];
    __shared__ float sb2v[64];

    int t = threadIdx.x;
    int row0 = blockIdx.x * 64;
    const float* W1r = W1 + (size_t)r * (128 * 64);
    const float* W2r = W2 + (size_t)r * (64 * 64);

    #pragma unroll
    for (int q = 0; q < 4; q++) {
        int f = t + 256 * q;
        int k = f >> 4, c = (f & 15) * 4;
        *(float4*)(sW + k * 64 + c) = *(const float4*)(W1r + k * 64 + c);
    }
    #pragma unroll
    for (int q = 0; q < 4; q++) {
        int f = t + 256 * q;
        int i = f & 63;
        int c = (f >> 6) * 4;
        int nrow = row0 + i;
        float4 xv = make_float4(0.f, 0.f, 0.f, 0.f);
        if (nrow < n_rows) {
            const float* src = (nrow < U) ? (user_emb + (size_t)nrow * 64)
                                          : (item_emb + (size_t)(nrow - U) * 64);
            xv = *(const float4*)(src + c);
        }
        int gi = i >> 2, w = i & 3;
        sX[(c + 0) * 64 + 4 * (gi ^ ((c + 0) & 15)) + w] = xv.x;
        sX[(c + 1) * 64 + 4 * (gi ^ ((c + 1) & 15)) + w] = xv.y;
        sX[(c + 2) * 64 + 4 * (gi ^ ((c + 2) & 15)) + w] = xv.z;
        sX[(c + 3) * 64 + 4 * (gi ^ ((c + 3) & 15)) + w] = xv.w;
    }
    if (t < 64) sc1[t] = c1_all[r * 64 + t];
    else if (t < 128) sb2v[t - 64] = b2[r * 64 + (t - 64)];
    __syncthreads();

    int gi = t & 15;
    int i0 = gi * 4, j0 = (t >> 4) * 4;
    float acc[4][4];
    #pragma unroll
    for (int a = 0; a < 4; a++)
        #pragma unroll
        for (int b = 0; b < 4; b++) acc[a][b] = sc1[j0 + b];
    for (int k = 0; k < 64; k++) {
        float4 xv = *(const float4*)(sX + k * 64 + 4 * (gi ^ (k & 15)));
        float4 wv = *(const float4*)(sW + k * 64 + j0);
        float xs[4] = {xv.x, xv.y, xv.z, xv.w};
        float ws[4] = {wv.x, wv.y, wv.z, wv.w};
        #pragma unroll
        for (int a = 0; a < 4; a++)
            #pragma unroll
            for (int b = 0; b < 4; b++) acc[a][b] += xs[a] * ws[b];
    }
    __syncthreads();

    #pragma unroll
    for (int b = 0; b < 4; b++) {
        int k = j0 + b;
        float4 tv;
        tv.x = (acc[0][b] >= 0.f) ? acc[0][b] : 0.01f * acc[0][b];
        tv.y = (acc[1][b] >= 0.f) ? acc[1][b] : 0.01f * acc[1][b];
        tv.z = (acc[2][b] >= 0.f) ? acc[2][b] : 0.01f * acc[2][b];
        tv.w = (acc[3][b] >= 0.f) ? acc[3][b] : 0.01f * acc[3][b];
        *(float4*)(sX + k * 64 + 4 * (gi ^ (k & 15))) = tv;
    }
    #pragma unroll
    for (int q = 0; q < 4; q++) {
        int f = t + 256 * q;
        int k = f >> 4, c = (f & 15) * 4;
        *(float4*)(sW + k * 64 + c) = *(const float4*)(W2r + k * 64 + c);
    }
    __syncthreads();

    #pragma unroll
    for (int a = 0; a < 4; a++)
        #pragma unroll
        for (int b = 0; b < 4; b++) acc[a][b] = sb2v[j0 + b];
    for (int k = 0; k < 64; k++) {
        float4 xv = *(const float4*)(sX + k * 64 + 4 * (gi ^ (k & 15)));
        float4 wv = *(const float4*)(sW + k * 64 + j0);
        float xs[4] = {xv.x, xv.y, xv.z, xv.w};
        float ws[4] = {wv.x, wv.y, wv.z, wv.w};
        #pragma unroll
        for (int a = 0; a < 4; a++)
            #pragma unroll
            for (int b = 0; b < 4; b++) acc[a][b] += xs[a] * ws[b];
    }
    #pragma unroll
    for (int a = 0; a < 4; a++) {
        int nrow = row0 + i0 + a;
        if (nrow < n_rows) {
            float4 hv = make_float4(acc[a][0], acc[a][1], acc[a][2], acc[a][3]);
            *(float4*)(prev + (size_t)nrow * 64 + j0) = hv;
            if (flag[nrow]) {
                float4 ov = *(const float4*)(out_acc + (size_t)nrow * 64 + j0);
                ov.x += hv.x; ov.y += hv.y; ov.z += hv.z; ov.w += hv.w;
                *(float4*)(out_acc + (size_t)nrow * 64 + j0) = ov;
            }
        }
    }
}

// ---------------------------------------------------------------------------
// Gather-SpMM (layers 0/1): wave = 1 row; 4 edge-groups x 16 lanes x float4
// (full 256B row consumed per gather). 8 edges in flight per wave.
// ---------------------------------------------------------------------------
__global__ __launch_bounds__(256) void spmm_kernel(
    const float* __restrict__ prev, float* __restrict__ next,
    float* __restrict__ out_acc, const int* __restrict__ rp,
    const uint2* __restrict__ rec, const unsigned char* __restrict__ flag, int n) {
    int wave = (int)((blockIdx.x * (unsigned)blockDim.x + threadIdx.x) >> 6);
    int lane = threadIdx.x & 63;
    if (wave >= n) return;
    int sub = lane >> 4;      // edge group 0..3
    int dl = lane & 15;       // dims [dl*4, dl*4+4)
    int s = rp[wave], e2 = rp[wave + 1];
    float ax = 0.f, ay = 0.f, az = 0.f, aw = 0.f;
    int e = s + sub;
    for (; e + 4 < e2; e += 8) {
        uint2 r0 = rec[e];
        uint2 r1 = rec[e + 4];
        float4 p0 = *(const float4*)(prev + (size_t)(r0.x & COLMASK) * 64 + dl * 4);
        float4 p1 = *(const float4*)(prev + (size_t)(r1.x & COLMASK) * 64 + dl * 4);
        float v0 = __uint_as_float(r0.y), v1 = __uint_as_float(r1.y);
        ax += v0 * p0.x; ay += v0 * p0.y; az += v0 * p0.z; aw += v0 * p0.w;
        ax += v1 * p1.x; ay += v1 * p1.y; az += v1 * p1.z; aw += v1 * p1.w;
    }
    if (e < e2) {
        uint2 r0 = rec[e];
        float4 p0 = *(const float4*)(prev + (size_t)(r0.x & COLMASK) * 64 + dl * 4);
        float v0 = __uint_as_float(r0.y);
        ax += v0 * p0.x; ay += v0 * p0.y; az += v0 * p0.z; aw += v0 * p0.w;
    }
    ax += __shfl_xor(ax, 16); ay += __shfl_xor(ay, 16);
    az += __shfl_xor(az, 16); aw += __shfl_xor(aw, 16);
    ax += __shfl_xor(ax, 32); ay += __shfl_xor(ay, 32);
    az += __shfl_xor(az, 32); aw += __shfl_xor(aw, 32);
    if (sub == 0) {
        *(float4*)(next + (size_t)wave * 64 + dl * 4) = make_float4(ax, ay, az, aw);
    } else if (sub == 1 && flag[wave]) {
        float* o = out_acc + (size_t)wave * 64 + dl * 4;
        float4 ov = *(const float4*)o;
        ov.x += ax; ov.y += ay; ov.z += az; ov.w += aw;
        *(float4*)o = ov;
    }
}

// ---------------------------------------------------------------------------
// Layer-2 (masked) SpMM: only rows in flist. Same float4-lane layout.
// ---------------------------------------------------------------------------
__global__ __launch_bounds__(256) void spmm_masked_kernel(
    const float* __restrict__ prev, float* __restrict__ out_acc,
    const int* __restrict__ rp, const uint2* __restrict__ rec,
    unsigned long long maskbits, const int* __restrict__ flist,
    const int* __restrict__ fcount) {
    int w = (int)((blockIdx.x * (unsigned)blockDim.x + threadIdx.x) >> 6);
    int lane = threadIdx.x & 63;
    if (w >= *fcount) return;
    int sub = lane >> 4;
    int dl = lane & 15;
    int row = flist[w];
    int s = rp[row], e2 = rp[row + 1];
    float ax = 0.f, ay = 0.f, az = 0.f, aw = 0.f;
    int e = s + sub;
    for (; e + 4 < e2; e += 8) {
        uint2 r0 = rec[e];
        uint2 r1 = rec[e + 4];
        float4 p0 = *(const float4*)(prev + (size_t)(r0.x & COLMASK) * 64 + dl * 4);
        float4 p1 = *(const float4*)(prev + (size_t)(r1.x & COLMASK) * 64 + dl * 4);
        float v0 = __uint_as_float(r0.y), v1 = __uint_as_float(r1.y);
        ax += v0 * p0.x; ay += v0 * p0.y; az += v0 * p0.z; aw += v0 * p0.w;
        ax += v1 * p1.x; ay += v1 * p1.y; az += v1 * p1.z; aw += v1 * p1.w;
    }
    if (e < e2) {
        uint2 r0 = rec[e];
        float4 p0 = *(const float4*)(prev + (size_t)(r0.x & COLMASK) * 64 + dl * 4);
        float v0 = __uint_as_float(r0.y);
        ax += v0 * p0.x; ay += v0 * p0.y; az += v0 * p0.z; aw += v0 * p0.w;
    }
    ax += __shfl_xor(ax, 16); ay += __shfl_xor(ay, 16);
    az += __shfl_xor(az, 16); aw += __shfl_xor(aw, 16);
    ax += __shfl_xor(ax, 32); ay += __shfl_xor(ay, 32);
    az += __shfl_xor(az, 32); aw += __shfl_xor(aw, 32);
    if (sub == 0) {
        const float* pv = prev + (size_t)row * 64 + dl * 4;
        float4 pvv = *(const float4*)pv;
        float rx = ((maskbits >> (dl * 4 + 0)) & 1ull) ? ax : pvv.x;
        float ry = ((maskbits >> (dl * 4 + 1)) & 1ull) ? ay : pvv.y;
        float rz = ((maskbits >> (dl * 4 + 2)) & 1ull) ? az : pvv.z;
        float rw = ((maskbits >> (dl * 4 + 3)) & 1ull) ? aw : pvv.w;
        float* o = out_acc + (size_t)row * 64 + dl * 4;
        float4 ov = *(const float4*)o;
        ov.x += rx; ov.y += ry; ov.z += rz; ov.w += rw;
        *(float4*)o = ov;
    }
}

// ---------------------------------------------------------------------------
// Final: out[b] = (1/R^2) * dot(out_acc[users[b]], out_acc[U+items[b]])
// ---------------------------------------------------------------------------
__global__ __launch_bounds__(256) void dot_kernel(
    const float* __restrict__ out_acc, const int* __restrict__ users,
    const int* __restrict__ items, float* __restrict__ out,
    int Bn, int U, float scale) {
    int w = (int)((blockIdx.x * (unsigned)blockDim.x + threadIdx.x) >> 6);
    int lane = threadIdx.x & 63;
    if (w >= Bn) return;
    int u = users[w], it = items[w];
    float a = out_acc[(size_t)u * 64 + lane];
    float c = out_acc[((size_t)(U + it)) * 64 + lane];
    float p = a * c;
    #pragma unroll
    for (int off = 32; off > 0; off >>= 1) p += __shfl_down(p, off);
    if (lane == 0) out[w] = p * scale;
}

// ---------------------------------------------------------------------------
extern "C" void kernel_launch(void* const* d_in, const int* in_sizes, int n_in,
                              void* d_out, int out_size, void* d_ws, size_t ws_size,
                              hipStream_t stream) {
    const int* users = (const int*)d_in[0];
    const int* items = (const int*)d_in[1];
    const float* user_emb = (const float*)d_in[2];
    const float* item_emb = (const float*)d_in[3];
    const float* rating_emb = (const float*)d_in[4];
    const float* W1 = (const float*)d_in[5];
    const float* b1 = (const float*)d_in[6];
    const float* W2 = (const float*)d_in[7];
    const float* b2 = (const float*)d_in[8];
    const int* rows = (const int*)d_in[9];
    const int* cols = (const int*)d_in[10];
    const float* vals = (const float*)d_in[11];
    float* out = (float*)d_out;

    const int Dd = 64;
    int U = in_sizes[2] / Dd;
    int I = in_sizes[3] / Dd;
    int R = in_sizes[4] / Dd;
    int N = U + I;
    int E = in_sizes[9] / R;
    int Bn = in_sizes[0];
    int K = (N + 63) / 64;          // row buckets; K+1 <= 2048
    int nb = (E + EPB - 1) / EPB;   // count/scatter blocks per rating

    char* p = (char*)d_ws;
    auto carve = [&](size_t bytes) -> char* {
        char* q = p;
        p += (bytes + 255) & ~(size_t)255;
        return q;
    };
    float* out_acc = (float*)carve((size_t)N * 64 * 4);
    float* bufA = (float*)carve((size_t)N * 64 * 4);
    float* bufB = (float*)carve((size_t)N * 64 * 4);
    uint2* rec = (uint2*)carve((size_t)E * 8);
    uint2* srec = (uint2*)carve((size_t)E * 8);
    int* gcnt = (int*)carve((size_t)R * K * 4);
    int* bptr = (int*)carve((size_t)R * (K + 1) * 4);
    int* blockBase = (int*)carve((size_t)R * nb * K * 4);
    int* row_ptr = (int*)carve((size_t)R * (N + 1) * 4);
    float* c1_all = (float*)carve((size_t)R * 64 * 4);
    unsigned char* flag = (unsigned char*)carve((size_t)N);
    int* flist = (int*)carve((size_t)2 * Bn * 4);
    int* fcount = (int*)carve(4);

    uint64_t maskbits = compute_mask_bits();

    hipMemsetAsync(out_acc, 0, (size_t)N * 64 * 4, stream);
    hipMemsetAsync(flag, 0, (size_t)N, stream);
    hipMemsetAsync(fcount, 0, 4, stream);
    hipMemsetAsync(gcnt, 0, (size_t)R * K * 4, stream);

    flag_kernel<<<(2 * Bn + 255) / 256, 256, 0, stream>>>(users, items, flag, Bn, U);
    flist_kernel<<<(N + 255) / 256, 256, 0, stream>>>(flag, flist, fcount, N);
    c1_kernel<<<R, 64, 0, stream>>>(rating_emb, W1, b1, c1_all);

    // Build pass A (batched) + per-rating scans
    dim3 cgrid(nb, R);
    bucket_count_kernel<<<cgrid, 1024, 0, stream>>>(rows, gcnt, blockBase, E, K, nb);
    bucket_scan_kernel<<<R, 256, 0, stream>>>(gcnt, bptr, K);

    int spmm_blocks = (N + 3) / 4;
    int masked_blocks = (2 * Bn + 3) / 4;
    for (int r = 0; r < R; r++) {
        const int* rows_r = rows + (size_t)r * E;
        const int* cols_r = cols + (size_t)r * E;
        const float* vals_r = vals + (size_t)r * E;
        const int* bptr_r = bptr + (size_t)r * (K + 1);
        const int* blockBase_r = blockBase + (size_t)r * nb * K;
        int* rp_r = row_ptr + (size_t)r * (N + 1);

        bucket_scatter_kernel<<<nb, 1024, 0, stream>>>(rows_r, cols_r, vals_r,
                                                       bptr_r, blockBase_r, rec,
                                                       E, K, nb);
        bucket_sort_kernel<<<K, 256, 0, stream>>>(rec, srec, bptr_r, rp_r, K, N);

        mlp_kernel<<<(N + 63) / 64, 256, 0, stream>>>(user_emb, item_emb, W1, W2,
                                                      c1_all, b2, bufA, out_acc,
                                                      flag, r, N, U);

        spmm_kernel<<<spmm_blocks, 256, 0, stream>>>(bufA, bufB, out_acc, rp_r,
                                                     srec, flag, N);
        spmm_kernel<<<spmm_blocks, 256, 0, stream>>>(bufB, bufA, out_acc, rp_r,
                                                     srec, flag, N);
        spmm_masked_kernel<<<masked_blocks, 256, 0, stream>>>(bufA, out_acc, rp_r,
                                                              srec, maskbits,
                                                              flist, fcount);
    }

    float scale = 1.0f / (float)(R * R);
    dot_kernel<<<(Bn * 64 + 255) / 256, 256, 0, stream>>>(out_acc, users, items, out,
                                                          Bn, U, scale);
}